// Round 1
// baseline (213.743 us; speedup 1.0000x reference)
//
#include <hip/hip_runtime.h>

// Problem constants (match reference)
#define BIMG 16
#define NROI 6000
#define NGT  256
#define TPOS 66
#define TNEG 134
#define TTOT 200
#define SORT_N 8192
#define EPSF 1e-8f

// ---------------- Kernel A: IoU + keys + argmax ----------------
// grid (24, 16), block 256. Each block: one image chunk of 250 rois.
__global__ void iou_keys_kernel(const float* __restrict__ rois,
                                const int* __restrict__ gt_ids,
                                const float* __restrict__ gt_boxes,
                                const float* __restrict__ pos_score,
                                const float* __restrict__ neg_score,
                                unsigned long long* __restrict__ pos_key,
                                unsigned long long* __restrict__ neg_key,
                                int* __restrict__ assign)
{
#pragma clang fp contract(off)
    const int b = blockIdx.y;
    __shared__ float4 s_gt[NGT];
    __shared__ float   s_area[NGT];
    __shared__ int     s_flag[NGT];   // 1 = non_crowd, 2 = crowd, 0 = neither

    for (int g = threadIdx.x; g < NGT; g += blockDim.x) {
        float4 gb = ((const float4*)(gt_boxes))[b * NGT + g];
        s_gt[g] = gb;
        s_area[g] = (gb.z - gb.x) * (gb.w - gb.y);
        bool valid = (gb.x != 0.f) || (gb.y != 0.f) || (gb.z != 0.f) || (gb.w != 0.f);
        int id = gt_ids[b * NGT + g];
        s_flag[g] = valid ? (id > 0 ? 1 : (id < 0 ? 2 : 0)) : 0;
    }
    __syncthreads();

    const int rois_per_block = (NROI + gridDim.x - 1) / gridDim.x;  // 250
    const int n0 = blockIdx.x * rois_per_block;
    const int n1 = min(n0 + rois_per_block, NROI);

    for (int n = n0 + (int)threadIdx.x; n < n1; n += blockDim.x) {
        float4 rb = ((const float4*)(rois))[b * NROI + n];
        bool rvalid = (rb.x != 0.f) || (rb.y != 0.f) || (rb.z != 0.f) || (rb.w != 0.f);
        float area_a = (rb.z - rb.x) * (rb.w - rb.y);

        float best = -1.0f;   // iou_nc_max (init matches where(..., -1.0))
        int   bestg = 0;      // jnp.argmax -> first occurrence
        float crmax = 0.0f;   // max(where(crowd, iou, 0))

        for (int g = 0; g < NGT; ++g) {
            int fl = s_flag[g];
            float4 gb = s_gt[g];
            float y1 = fmaxf(rb.x, gb.x);
            float x1 = fmaxf(rb.y, gb.y);
            float y2 = fminf(rb.z, gb.z);
            float x2 = fminf(rb.w, gb.w);
            float ih = fmaxf(y2 - y1, 0.0f);
            float iw = fmaxf(x2 - x1, 0.0f);
            float inter = ih * iw;
            float uni = area_a + s_area[g] - inter;   // (area_a + area_b) - inter
            float iou = inter / fmaxf(uni, EPSF);
            float vnc = (fl == 1) ? iou : -1.0f;
            if (vnc > best) { best = vnc; bestg = g; }  // strict > => first max
            float vcr = (fl == 2) ? iou : 0.0f;
            crmax = fmaxf(crmax, vcr);
        }

        unsigned long long pk = 0ull, nk = 0ull;
        if (rvalid) {
            if (best >= 0.5f) {
                unsigned int sb = __float_as_uint(pos_score[b * NROI + n]);
                pk = ((unsigned long long)sb << 32) | (unsigned int)(~n);
            }
            if ((best < 0.5f) && (crmax < 0.001f)) {
                unsigned int sb = __float_as_uint(neg_score[b * NROI + n]);
                nk = ((unsigned long long)sb << 32) | (unsigned int)(~n);
            }
        }
        pos_key[b * NROI + n] = pk;
        neg_key[b * NROI + n] = nk;
        assign[b * NROI + n] = bestg;
    }
}

// ---------------- Kernel B: bitonic top-K sort (descending) ----------------
// grid 32 (= 16 images x {pos,neg}), block 1024, 64 KB LDS.
__global__ __launch_bounds__(1024)
void topk_sort_kernel(const unsigned long long* __restrict__ pos_key,
                      const unsigned long long* __restrict__ neg_key,
                      int* __restrict__ sel,      // [16][2][TNEG]
                      int* __restrict__ counts)   // [16][2] = total valid in mask
{
    __shared__ unsigned long long s_key[SORT_N];  // exactly 64 KiB
    const int b = blockIdx.x >> 1;
    const int which = blockIdx.x & 1;
    const unsigned long long* src = which ? neg_key : pos_key;

    for (int i = threadIdx.x; i < SORT_N; i += 1024)
        s_key[i] = (i < NROI) ? src[b * NROI + i] : 0ull;
    __syncthreads();

    // descending bitonic sort
    for (int k = 2; k <= SORT_N; k <<= 1) {
        for (int j = k >> 1; j > 0; j >>= 1) {
            for (int i = threadIdx.x; i < SORT_N; i += 1024) {
                int l = i ^ j;
                if (l > i) {
                    unsigned long long a = s_key[i];
                    unsigned long long c = s_key[l];
                    bool sw = ((i & k) == 0) ? (a < c) : (a > c);
                    if (sw) { s_key[i] = c; s_key[l] = a; }
                }
            }
            __syncthreads();
        }
    }

    if (threadIdx.x == 0) {
        // first zero key == number of mask-valid entries (keys of valid are nonzero)
        int lo = 0, hi = SORT_N;
        while (lo < hi) {
            int mid = (lo + hi) >> 1;
            if (s_key[mid] != 0ull) lo = mid + 1; else hi = mid;
        }
        counts[b * 2 + which] = lo;
    }
    const int K = which ? TNEG : TPOS;
    if ((int)threadIdx.x < K) {
        unsigned long long key = s_key[threadIdx.x];
        int n = (int)(~(unsigned int)(key & 0xFFFFFFFFull));
        sel[(b * 2 + which) * TNEG + threadIdx.x] = (key != 0ull) ? n : 0;
    }
}

// ---------------- Kernel C: gather + epilogue ----------------
// grid 16, block 256 (threads 0..199 used)
__global__ void gather_kernel(const float* __restrict__ rois,
                              const int* __restrict__ gt_ids,
                              const float* __restrict__ gt_boxes,
                              const int* __restrict__ sel,
                              const int* __restrict__ counts,
                              const int* __restrict__ assign,
                              float* __restrict__ out)
{
#pragma clang fp contract(off)
    const int b = blockIdx.x;
    const int t = threadIdx.x;
    if (t >= TTOT) return;

    const int pos_total = counts[b * 2 + 0];
    const int neg_total = counts[b * 2 + 1];
    const int pos_count = min(pos_total, TPOS);
    const float ratio_inv = (float)(1.0 / 0.33);                 // f32(1/RATIO), matches jnp.float32
    const int neg_target = (int)(ratio_inv * (float)pos_count) - pos_count;
    const int neg_count = min(neg_total, min(neg_target, TNEG)); // may be <= 0

    float* out_rois = out;                                // [16][200][4]
    float* out_ids  = out + BIMG * TTOT * 4;              // [16][200]
    float* out_off  = out + BIMG * TTOT * 4 + BIMG * TTOT;// [16][200][4]

    const int base = b * TTOT + t;
    float4 ro  = make_float4(0.f, 0.f, 0.f, 0.f);
    float  idv = 0.f;
    float4 off = make_float4(0.f, 0.f, 0.f, 0.f);

    if (t < TPOS) {
        if (t < pos_count) {
            int n = sel[(b * 2 + 0) * TNEG + t];
            float4 rb = ((const float4*)(rois))[b * NROI + n];
            ro = rb;
            int g = assign[b * NROI + n];
            float4 gb = ((const float4*)(gt_boxes))[b * NGT + g];
            idv = (float)gt_ids[b * NGT + g];

            float h  = fmaxf(rb.z - rb.x, EPSF);
            float w  = fmaxf(rb.w - rb.y, EPSF);
            float cy = rb.x + 0.5f * h;
            float cx = rb.y + 0.5f * w;
            float gh = fmaxf(gb.z - gb.x, EPSF);
            float gw = fmaxf(gb.w - gb.y, EPSF);
            float gcy = gb.x + 0.5f * gh;
            float gcx = gb.y + 0.5f * gw;
            off.x = ((gcy - cy) / h) / 0.1f;
            off.y = ((gcx - cx) / w) / 0.1f;
            off.z = logf(gh / h) / 0.2f;
            off.w = logf(gw / w) / 0.2f;
        }
    } else {
        int q = t - TPOS;
        if (q < neg_count) {
            int n = sel[(b * 2 + 1) * TNEG + q];
            ro = ((const float4*)(rois))[b * NROI + n];
        }
    }

    ((float4*)out_rois)[base] = ro;
    out_ids[base] = idv;
    ((float4*)out_off)[base] = off;
}

extern "C" void kernel_launch(void* const* d_in, const int* in_sizes, int n_in,
                              void* d_out, int out_size, void* d_ws, size_t ws_size,
                              hipStream_t stream) {
    const float* rois      = (const float*)d_in[0];
    const int*   gt_ids    = (const int*)d_in[1];
    const float* gt_boxes  = (const float*)d_in[2];
    const float* pos_score = (const float*)d_in[3];
    const float* neg_score = (const float*)d_in[4];
    float* out = (float*)d_out;

    // workspace layout (all 8-byte aligned)
    char* ws = (char*)d_ws;
    unsigned long long* pos_key = (unsigned long long*)(ws + 0);            // 768000 B
    unsigned long long* neg_key = (unsigned long long*)(ws + 768000);       // 768000 B
    int* assign = (int*)(ws + 1536000);                                     // 384000 B
    int* counts = (int*)(ws + 1920000);                                     // 128 B
    int* sel    = (int*)(ws + 1920128);                                     // 17152 B

    dim3 gridA(24, BIMG);
    iou_keys_kernel<<<gridA, 256, 0, stream>>>(rois, gt_ids, gt_boxes,
                                               pos_score, neg_score,
                                               pos_key, neg_key, assign);
    topk_sort_kernel<<<BIMG * 2, 1024, 0, stream>>>(pos_key, neg_key, sel, counts);
    gather_kernel<<<BIMG, 256, 0, stream>>>(rois, gt_ids, gt_boxes,
                                            sel, counts, assign, out);
}

// Round 2
// 110.440 us; speedup vs baseline: 1.9354x; 1.9354x over previous
//
#include <hip/hip_runtime.h>

// Problem constants (match reference)
#define BIMG 16
#define NROI 6000
#define NGT  256
#define TPOS 66
#define TNEG 134
#define TTOT 200
#define EPSF 1e-8f

typedef unsigned long long u64;
typedef unsigned int u32;

// ---------------- Kernel A0: pack per-gt data ----------------
// [b][g] -> 8 floats {y1,x1,y2,x2,area,flag,0,0}; grid 16, block 256
__global__ void pack_gt_kernel(const int* __restrict__ gt_ids,
                               const float* __restrict__ gt_boxes,
                               float* __restrict__ gt_pack)
{
#pragma clang fp contract(off)
    const int b = blockIdx.x;
    const int g = threadIdx.x;
    float4 gb = ((const float4*)gt_boxes)[b * NGT + g];
    float area = (gb.z - gb.x) * (gb.w - gb.y);
    bool valid = (gb.x != 0.f) || (gb.y != 0.f) || (gb.z != 0.f) || (gb.w != 0.f);
    int id = gt_ids[b * NGT + g];
    float flag = valid ? (id > 0 ? 1.f : (id < 0 ? 2.f : 0.f)) : 0.f;
    float4* dst = (float4*)(gt_pack + (size_t)(b * NGT + g) * 8);
    dst[0] = gb;
    dst[1] = make_float4(area, flag, 0.f, 0.f);
}

// ---------------- Kernel A: IoU + keys + argmax ----------------
// 4 threads per ROI (each covers 64 gts), shfl merge. grid (94,16), block 256.
__global__ __launch_bounds__(256)
void iou_keys_kernel(const float* __restrict__ rois,
                     const float* __restrict__ gt_pack,
                     const float* __restrict__ pos_score,
                     const float* __restrict__ neg_score,
                     u64* __restrict__ pos_key,
                     u64* __restrict__ neg_key,
                     unsigned char* __restrict__ assign)
{
#pragma clang fp contract(off)
    const int b = blockIdx.y;
    __shared__ float4 s_pack[NGT * 2];   // 8 KB
    {
        const float4* gp = (const float4*)(gt_pack + (size_t)b * NGT * 8);
        s_pack[threadIdx.x] = gp[threadIdx.x];
        s_pack[threadIdx.x + 256] = gp[threadIdx.x + 256];
    }
    __syncthreads();

    const int r_local = threadIdx.x >> 2;       // 0..63
    const int sub = threadIdx.x & 3;            // gt-range 0..3
    const int n = blockIdx.x * 64 + r_local;
    const int n_eff = min(n, NROI - 1);

    float4 rb = ((const float4*)rois)[b * NROI + n_eff];
    const bool rvalid = (rb.x != 0.f) || (rb.y != 0.f) || (rb.z != 0.f) || (rb.w != 0.f);
    const float area_a = (rb.z - rb.x) * (rb.w - rb.y);

    float best = -1.0f;       // iou_nc_max partial (init matches where(..., -1.0))
    int bestg = sub * 64;     // first index of this range (argmax -> first occurrence)
    float crmax = 0.0f;

    const int g0 = sub * 64;
    for (int gg = 0; gg < 64; ++gg) {
        int g = g0 + gg;
        float4 p0 = s_pack[g * 2];
        float4 p1 = s_pack[g * 2 + 1];
        float y1 = fmaxf(rb.x, p0.x);
        float x1 = fmaxf(rb.y, p0.y);
        float y2 = fminf(rb.z, p0.z);
        float x2 = fminf(rb.w, p0.w);
        float ih = fmaxf(y2 - y1, 0.0f);
        float iw = fmaxf(x2 - x1, 0.0f);
        float inter = ih * iw;
        float uni = fmaxf(area_a + p1.x - inter, EPSF);  // (a+b)-inter, then max eps
        float iou = inter / uni;                          // precise f32 div
        float vnc = (p1.y == 1.f) ? iou : -1.0f;
        if (vnc > best) { best = vnc; bestg = g; }        // strict > => first max
        float vcr = (p1.y == 2.f) ? iou : 0.0f;
        crmax = fmaxf(crmax, vcr);
    }

    // butterfly merge across the 4 sub-lanes (quad)
    for (int m = 1; m <= 2; m <<= 1) {
        float ov = __shfl_xor(best, m);
        int   og = __shfl_xor(bestg, m);
        float oc = __shfl_xor(crmax, m);
        if (ov > best || (ov == best && og < bestg)) { best = ov; bestg = og; }
        crmax = fmaxf(crmax, oc);
    }

    if (sub == 0 && n < NROI) {
        u64 pk = 0ull, nk = 0ull;
        if (rvalid) {
            if (best >= 0.5f) {
                u32 sb = __float_as_uint(pos_score[b * NROI + n]);
                pk = ((u64)sb << 32) | (u32)(~n);
            }
            if ((best < 0.5f) && (crmax < 0.001f)) {
                u32 sb = __float_as_uint(neg_score[b * NROI + n]);
                nk = ((u64)sb << 32) | (u32)(~n);
            }
        }
        pos_key[b * NROI + n] = pk;
        neg_key[b * NROI + n] = nk;
        assign[b * NROI + n] = (unsigned char)bestg;
    }
}

// ---------------- Kernel B: exact radix top-K select ----------------
// grid 32 (= 16 images x {pos,neg}), block 1024. Keys in registers (6/thread).
#define BSEL 1024
#define SLOTS 6
__global__ __launch_bounds__(BSEL)
void select_kernel(const u64* __restrict__ pos_key,
                   const u64* __restrict__ neg_key,
                   int* __restrict__ sel,      // [16][2][TNEG]
                   int* __restrict__ counts)   // [16][2] = total valid in mask
{
    __shared__ u32 s_hist[16][256];   // per-wave histograms, 16 KB
    __shared__ u32 s_tot[256];
    __shared__ u32 s_sufl[64];
    __shared__ u64 s_comp[TNEG];
    __shared__ int s_cnt;
    __shared__ int s_count;
    __shared__ int s_pick;
    __shared__ u32 s_higher;

    const int b = blockIdx.x >> 1;
    const int which = blockIdx.x & 1;
    const int K = which ? TNEG : TPOS;
    const u64* src = (which ? neg_key : pos_key) + (size_t)b * NROI;
    const int tid = threadIdx.x;
    const int wid = tid >> 6;

    u64 key[SLOTS];
    int myvalid = 0;
    for (int s = 0; s < SLOTS; ++s) {
        int idx = s * BSEL + tid;
        key[s] = (idx < NROI) ? src[idx] : 0ull;
        myvalid += (key[s] != 0ull);
    }

    // count valid via wave reduce + LDS
    for (int off = 1; off < 64; off <<= 1) myvalid += __shfl_xor(myvalid, off);
    if (tid == 0) s_count = 0;
    __syncthreads();
    if ((tid & 63) == 0) atomicAdd(&s_count, myvalid);
    __syncthreads();
    const int count = s_count;
    if (tid == 0) counts[b * 2 + which] = count;

    if (count > 0) {
        int Krem = min(K, count);
        u64 prefix = 0ull, mask = 0ull;

        for (int p = 7; p >= 0; --p) {
            const int shift = p * 8;
            // clear histograms
            for (int i = tid; i < 16 * 256; i += BSEL) ((u32*)s_hist)[i] = 0;
            __syncthreads();
            // fill (per-wave hist to cut atomic skew)
            for (int s = 0; s < SLOTS; ++s) {
                u64 k = key[s];
                if ((k & mask) == prefix) {
                    u32 byte = (u32)(k >> shift) & 255u;
                    atomicAdd(&s_hist[wid][byte], 1u);
                }
            }
            __syncthreads();
            // reduce 16 -> 1
            if (tid < 256) {
                u32 t = 0;
                for (int w = 0; w < 16; ++w) t += s_hist[w][tid];
                s_tot[tid] = t;
            }
            __syncthreads();
            // suffix sums over 4-bucket groups, one wave
            if (tid < 64) {
                int l = tid;
                u32 x = s_tot[4 * l] + s_tot[4 * l + 1] + s_tot[4 * l + 2] + s_tot[4 * l + 3];
                u32 suf = x;
                for (int off = 1; off < 64; off <<= 1) {
                    u32 v = __shfl_down(suf, off);
                    if (l + off < 64) suf += v;
                }
                s_sufl[l] = suf;   // sum over buckets >= 4l
            }
            __syncthreads();
            // per-bucket suffix; pick target byte
            if (tid < 256) {
                int l = tid >> 2;
                u32 suffix = s_sufl[l];
                for (int j = 4 * l; j < tid; ++j) suffix -= s_tot[j];
                u32 sufnext = suffix - s_tot[tid];          // count with byte > tid
                if (suffix >= (u32)Krem && sufnext < (u32)Krem) {
                    s_pick = tid;
                    s_higher = sufnext;
                }
            }
            __syncthreads();
            prefix |= ((u64)(u32)s_pick) << shift;
            mask |= (0xFFull << shift);
            Krem -= (int)s_higher;
            __syncthreads();
        }
        // prefix == exact Krem-th largest key (keys unique). Gather keys >= prefix.
        if (tid == 0) s_cnt = 0;
        __syncthreads();
        for (int s = 0; s < SLOTS; ++s) {
            u64 k = key[s];
            if (k >= prefix) {
                int pos = atomicAdd(&s_cnt, 1);
                s_comp[pos] = k;
            }
        }
        __syncthreads();
        const int Ksel = s_cnt;   // == min(K, count)
        if (tid < Ksel) {
            u64 k = s_comp[tid];
            int rank = 0;
            for (int j = 0; j < Ksel; ++j) rank += (s_comp[j] > k);
            int n = (int)(~(u32)(k & 0xFFFFFFFFull));
            sel[(b * 2 + which) * TNEG + rank] = n;
        }
    }
}

// ---------------- Kernel C: gather + epilogue ----------------
// grid 16, block 256 (threads 0..199 used)
__global__ void gather_kernel(const float* __restrict__ rois,
                              const int* __restrict__ gt_ids,
                              const float* __restrict__ gt_boxes,
                              const int* __restrict__ sel,
                              const int* __restrict__ counts,
                              const unsigned char* __restrict__ assign,
                              float* __restrict__ out)
{
#pragma clang fp contract(off)
    const int b = blockIdx.x;
    const int t = threadIdx.x;
    if (t >= TTOT) return;

    const int pos_total = counts[b * 2 + 0];
    const int neg_total = counts[b * 2 + 1];
    const int pos_count = min(pos_total, TPOS);
    const float ratio_inv = (float)(1.0 / 0.33);                 // f32(1/RATIO)
    const int neg_target = (int)(ratio_inv * (float)pos_count) - pos_count;
    const int neg_count = min(neg_total, min(neg_target, TNEG));

    float* out_rois = out;                                 // [16][200][4]
    float* out_ids  = out + BIMG * TTOT * 4;               // [16][200]
    float* out_off  = out + BIMG * TTOT * 4 + BIMG * TTOT; // [16][200][4]

    const int base = b * TTOT + t;
    float4 ro  = make_float4(0.f, 0.f, 0.f, 0.f);
    float  idv = 0.f;
    float4 off = make_float4(0.f, 0.f, 0.f, 0.f);

    if (t < TPOS) {
        if (t < pos_count) {
            int n = sel[(b * 2 + 0) * TNEG + t];
            float4 rb = ((const float4*)rois)[b * NROI + n];
            ro = rb;
            int g = (int)assign[b * NROI + n];
            float4 gb = ((const float4*)gt_boxes)[b * NGT + g];
            idv = (float)gt_ids[b * NGT + g];

            float h  = fmaxf(rb.z - rb.x, EPSF);
            float w  = fmaxf(rb.w - rb.y, EPSF);
            float cy = rb.x + 0.5f * h;
            float cx = rb.y + 0.5f * w;
            float gh = fmaxf(gb.z - gb.x, EPSF);
            float gw = fmaxf(gb.w - gb.y, EPSF);
            float gcy = gb.x + 0.5f * gh;
            float gcx = gb.y + 0.5f * gw;
            off.x = ((gcy - cy) / h) / 0.1f;
            off.y = ((gcx - cx) / w) / 0.1f;
            off.z = logf(gh / h) / 0.2f;
            off.w = logf(gw / w) / 0.2f;
        }
    } else {
        int q = t - TPOS;
        if (q < neg_count) {
            int n = sel[(b * 2 + 1) * TNEG + q];
            ro = ((const float4*)rois)[b * NROI + n];
        }
    }

    ((float4*)out_rois)[base] = ro;
    out_ids[base] = idv;
    ((float4*)out_off)[base] = off;
}

extern "C" void kernel_launch(void* const* d_in, const int* in_sizes, int n_in,
                              void* d_out, int out_size, void* d_ws, size_t ws_size,
                              hipStream_t stream) {
    const float* rois      = (const float*)d_in[0];
    const int*   gt_ids    = (const int*)d_in[1];
    const float* gt_boxes  = (const float*)d_in[2];
    const float* pos_score = (const float*)d_in[3];
    const float* neg_score = (const float*)d_in[4];
    float* out = (float*)d_out;

    // workspace layout (8-byte aligned); total ~1.78 MB
    char* ws = (char*)d_ws;
    u64* pos_key = (u64*)(ws + 0);                      //  768000 B
    u64* neg_key = (u64*)(ws + 768000);                 //  768000 B
    float* gt_pack = (float*)(ws + 1536000);            //  131072 B (16*256*8*4)
    unsigned char* assign = (unsigned char*)(ws + 1667072); // 96000 B
    int* counts = (int*)(ws + 1763072);                 //     128 B
    int* sel    = (int*)(ws + 1763200);                 //   17152 B

    pack_gt_kernel<<<BIMG, NGT, 0, stream>>>(gt_ids, gt_boxes, gt_pack);
    dim3 gridA((NROI + 63) / 64, BIMG);                 // 94 x 16
    iou_keys_kernel<<<gridA, 256, 0, stream>>>(rois, gt_pack, pos_score, neg_score,
                                               pos_key, neg_key, assign);
    select_kernel<<<BIMG * 2, BSEL, 0, stream>>>(pos_key, neg_key, sel, counts);
    gather_kernel<<<BIMG, 256, 0, stream>>>(rois, gt_ids, gt_boxes,
                                            sel, counts, assign, out);
}

// Round 3
// 105.837 us; speedup vs baseline: 2.0195x; 1.0435x over previous
//
#include <hip/hip_runtime.h>

// Problem constants (match reference)
#define BIMG 16
#define NROI 6000
#define NGT  256
#define TPOS 66
#define TNEG 134
#define TTOT 200
#define EPSF 1e-8f
#define INVALID_SCORE 0xFFFFFFFFu

typedef unsigned long long u64;
typedef unsigned int u32;
typedef unsigned char u8;

// ---------------- Kernel 1: fused gt-pack + IoU + score-keys + argmax ----------------
// 8 threads per ROI, each covering a stride-8 gt range (bank-conflict-free).
// grid (188, 16), block 256 -> 32 ROIs/block, 3008 blocks (~8 waves/SIMD resident).
__global__ __launch_bounds__(256)
void iou_keys_kernel(const float* __restrict__ rois,
                     const int* __restrict__ gt_ids,
                     const float* __restrict__ gt_boxes,
                     const float* __restrict__ pos_score,
                     const float* __restrict__ neg_score,
                     u32* __restrict__ pos_s,
                     u32* __restrict__ neg_s,
                     u8* __restrict__ assign)
{
#pragma clang fp contract(off)
    const int b = blockIdx.y;
    __shared__ float4 s_box[NGT];
    __shared__ float2 s_af[NGT];    // {area, flag} flag: 1=non_crowd 2=crowd 0=neither
    {
        const int g = threadIdx.x;  // 256 threads, 256 gts
        float4 gb = ((const float4*)gt_boxes)[b * NGT + g];
        s_box[g] = gb;
        float area = (gb.z - gb.x) * (gb.w - gb.y);
        bool valid = (gb.x != 0.f) || (gb.y != 0.f) || (gb.z != 0.f) || (gb.w != 0.f);
        int id = gt_ids[b * NGT + g];
        float flag = valid ? (id > 0 ? 1.f : (id < 0 ? 2.f : 0.f)) : 0.f;
        s_af[g] = make_float2(area, flag);
    }
    __syncthreads();

    const int r_local = threadIdx.x >> 3;   // 0..31
    const int sub = threadIdx.x & 7;        // stride-8 gt partition
    const int n = blockIdx.x * 32 + r_local;
    const int n_eff = min(n, NROI - 1);

    float4 rb = ((const float4*)rois)[b * NROI + n_eff];
    const bool rvalid = (rb.x != 0.f) || (rb.y != 0.f) || (rb.z != 0.f) || (rb.w != 0.f);
    const float area_a = (rb.z - rb.x) * (rb.w - rb.y);

    float best = -1.0f;     // iou_nc_max partial (matches where(..., -1.0) init)
    int bestg = sub;        // first g of this thread's range (argmax first-occurrence)
    float crmax = 0.0f;

    for (int gg = 0; gg < 32; ++gg) {
        const int g = (gg << 3) | sub;      // ascending within thread
        float4 p0 = s_box[g];
        float2 af = s_af[g];
        float y1 = fmaxf(rb.x, p0.x);
        float x1 = fmaxf(rb.y, p0.y);
        float y2 = fminf(rb.z, p0.z);
        float x2 = fminf(rb.w, p0.w);
        float ih = fmaxf(y2 - y1, 0.0f);
        float iw = fmaxf(x2 - x1, 0.0f);
        float inter = ih * iw;
        float uni = fmaxf(area_a + af.x - inter, EPSF);  // (a+b)-inter then max eps
        float iou = inter / uni;                          // precise f32 div (matches np)
        float vnc = (af.y == 1.f) ? iou : -1.0f;
        if (vnc > best) { best = vnc; bestg = g; }        // strict > => first max
        float vcr = (af.y == 2.f) ? iou : 0.0f;
        crmax = fmaxf(crmax, vcr);
    }

    // butterfly merge across the 8 sub-lanes; tie -> smaller g (first occurrence)
    for (int m = 1; m <= 4; m <<= 1) {
        float ov = __shfl_xor(best, m);
        int   og = __shfl_xor(bestg, m);
        float oc = __shfl_xor(crmax, m);
        if (ov > best || (ov == best && og < bestg)) { best = ov; bestg = og; }
        crmax = fmaxf(crmax, oc);
    }

    if (sub == 0 && n < NROI) {
        u32 ps = INVALID_SCORE, ns = INVALID_SCORE;
        if (rvalid) {
            if (best >= 0.5f)
                ps = __float_as_uint(pos_score[b * NROI + n]);   // in [0,1): bits < 2^30
            if ((best < 0.5f) && (crmax < 0.001f))
                ns = __float_as_uint(neg_score[b * NROI + n]);
        }
        pos_s[b * NROI + n] = ps;
        neg_s[b * NROI + n] = ns;
        assign[b * NROI + n] = (u8)bestg;
    }
}

// ---------------- Kernel 2: per-image radix top-K select (x2) + gather epilogue ----
// grid 16 (one block per image), block 512. 43-bit key = score_bits<<13 | (8191-n):
// order-isomorphic to (-score, index) stable argsort. 4 passes of 11-bit digits.
#define BSEL 512
#define SLOTS 12            // 512*12 = 6144 >= 6000

__device__ __forceinline__ int radix_select(const u32* __restrict__ src, int K,
                                            int tid, int lane, int w,
                                            u32* s_hist, u32* s_wtot, u32* s_wsuf,
                                            int* s_pick, u32* s_higher,
                                            int* s_count, u64* s_comp, int* s_cnt,
                                            int* s_sel /* out: ranked roi indices */)
{
    // load scores (keys) into registers
    u32 sc[SLOTS];
    int myvalid = 0;
    for (int s = 0; s < SLOTS; ++s) {
        int idx = s * BSEL + tid;
        sc[s] = (idx < NROI) ? src[idx] : INVALID_SCORE;
        myvalid += (sc[s] != INVALID_SCORE);
    }
    for (int off = 1; off < 64; off <<= 1) myvalid += __shfl_xor(myvalid, off);
    if (tid == 0) *s_count = 0;
    __syncthreads();
    if (lane == 0) atomicAdd(s_count, (u32)myvalid);
    __syncthreads();
    const int total = *s_count;
    int Krem = min(K, total);
    if (Krem <= 0) return total;   // uniform branch across block

    u64 prefix = 0ull, mask = 0ull;
    for (int p = 3; p >= 0; --p) {
        const int shift = p * 11;
        for (int i = tid; i < 2048; i += BSEL) s_hist[i] = 0;
        __syncthreads();
        for (int s = 0; s < SLOTS; ++s) {
            if (sc[s] != INVALID_SCORE) {
                u64 k = ((u64)sc[s] << 13) | (u64)(8191 - (s * BSEL + tid));
                if ((k & mask) == prefix)
                    atomicAdd(&s_hist[(u32)(k >> shift) & 2047u], 1u);
            }
        }
        __syncthreads();
        // block-wide inclusive suffix scan over 2048 buckets (4 per thread)
        u32 local = s_hist[4 * tid] + s_hist[4 * tid + 1]
                  + s_hist[4 * tid + 2] + s_hist[4 * tid + 3];
        u32 suf = local;
        for (int off = 1; off < 64; off <<= 1) {
            u32 v = __shfl_down(suf, off);
            if (lane + off < 64) suf += v;
        }
        if (lane == 0) s_wtot[w] = suf;   // wave total
        __syncthreads();
        if (tid < 8) {
            u32 t = 0;
            for (int j = tid + 1; j < 8; ++j) t += s_wtot[j];
            s_wsuf[tid] = t;              // strict-suffix of later waves
        }
        __syncthreads();
        u32 Sincl = suf + s_wsuf[w];      // suffix including bucket 4*tid
        for (int k2 = 0; k2 < 4; ++k2) {
            u32 h = s_hist[4 * tid + k2];
            u32 Snext = Sincl - h;        // count with digit > this bucket
            if (Sincl >= (u32)Krem && Snext < (u32)Krem) {  // unique crossing
                *s_pick = 4 * tid + k2;
                *s_higher = Snext;
            }
            Sincl = Snext;
        }
        __syncthreads();
        prefix |= ((u64)(u32)(*s_pick)) << shift;
        mask   |= (2047ull << shift);
        Krem   -= (int)(*s_higher);
        __syncthreads();
    }
    // prefix == exact Krem-th largest key (keys unique). Gather keys >= prefix.
    if (tid == 0) *s_cnt = 0;
    __syncthreads();
    for (int s = 0; s < SLOTS; ++s) {
        if (sc[s] != INVALID_SCORE) {
            u64 k = ((u64)sc[s] << 13) | (u64)(8191 - (s * BSEL + tid));
            if (k >= prefix) {
                int pos = atomicAdd(s_cnt, 1);
                s_comp[pos] = k;
            }
        }
    }
    __syncthreads();
    const int Ksel = *s_cnt;              // == min(K, total)
    if (tid < Ksel) {
        u64 k = s_comp[tid];
        int rank = 0;
        for (int j = 0; j < Ksel; ++j) rank += (s_comp[j] > k);
        s_sel[rank] = 8191 - (int)(k & 8191ull);
    }
    __syncthreads();
    return total;
}

__global__ __launch_bounds__(BSEL)
void select_gather_kernel(const float* __restrict__ rois,
                          const int* __restrict__ gt_ids,
                          const float* __restrict__ gt_boxes,
                          const u32* __restrict__ pos_s,
                          const u32* __restrict__ neg_s,
                          const u8* __restrict__ assign,
                          float* __restrict__ out)
{
#pragma clang fp contract(off)
    __shared__ u32 s_hist[2048];
    __shared__ u32 s_wtot[8];
    __shared__ u32 s_wsuf[8];
    __shared__ int s_pick;
    __shared__ u32 s_higher;
    __shared__ int s_count;
    __shared__ u64 s_comp[TNEG];
    __shared__ int s_cnt;
    __shared__ int s_selpos[TPOS];
    __shared__ int s_selneg[TNEG];

    const int b = blockIdx.x;
    const int tid = threadIdx.x;
    const int lane = tid & 63;
    const int w = tid >> 6;

    const int pos_total = radix_select(pos_s + (size_t)b * NROI, TPOS, tid, lane, w,
                                       s_hist, s_wtot, s_wsuf, &s_pick, &s_higher,
                                       &s_count, s_comp, &s_cnt, s_selpos);
    const int pos_count = min(pos_total, TPOS);
    const float ratio_inv = (float)(1.0 / 0.33);                 // f32(1/RATIO)
    const int neg_target = (int)(ratio_inv * (float)pos_count) - pos_count;
    const int Kneg = min(neg_target, TNEG);
    int neg_count = 0;
    if (Kneg > 0) {                                              // uniform branch
        const int neg_total = radix_select(neg_s + (size_t)b * NROI, Kneg, tid, lane, w,
                                           s_hist, s_wtot, s_wsuf, &s_pick, &s_higher,
                                           &s_count, s_comp, &s_cnt, s_selneg);
        neg_count = min(neg_total, Kneg);
    }

    // ---- gather epilogue (threads 0..199) ----
    if (tid < TTOT) {
        float* out_rois = out;                                 // [16][200][4]
        float* out_ids  = out + BIMG * TTOT * 4;               // [16][200]
        float* out_off  = out + BIMG * TTOT * 4 + BIMG * TTOT; // [16][200][4]
        const int base = b * TTOT + tid;

        float4 ro  = make_float4(0.f, 0.f, 0.f, 0.f);
        float  idv = 0.f;
        float4 off = make_float4(0.f, 0.f, 0.f, 0.f);

        if (tid < TPOS) {
            if (tid < pos_count) {
                int n = s_selpos[tid];
                float4 rb = ((const float4*)rois)[b * NROI + n];
                ro = rb;
                int g = (int)assign[b * NROI + n];
                float4 gb = ((const float4*)gt_boxes)[b * NGT + g];
                idv = (float)gt_ids[b * NGT + g];

                float h  = fmaxf(rb.z - rb.x, EPSF);
                float wd = fmaxf(rb.w - rb.y, EPSF);
                float cy = rb.x + 0.5f * h;
                float cx = rb.y + 0.5f * wd;
                float gh = fmaxf(gb.z - gb.x, EPSF);
                float gw = fmaxf(gb.w - gb.y, EPSF);
                float gcy = gb.x + 0.5f * gh;
                float gcx = gb.y + 0.5f * gw;
                off.x = ((gcy - cy) / h)  / 0.1f;
                off.y = ((gcx - cx) / wd) / 0.1f;
                off.z = logf(gh / h)  / 0.2f;
                off.w = logf(gw / wd) / 0.2f;
            }
        } else {
            int q = tid - TPOS;
            if (q < neg_count) {
                int n = s_selneg[q];
                ro = ((const float4*)rois)[b * NROI + n];
            }
        }

        ((float4*)out_rois)[base] = ro;
        out_ids[base] = idv;
        ((float4*)out_off)[base] = off;
    }
}

extern "C" void kernel_launch(void* const* d_in, const int* in_sizes, int n_in,
                              void* d_out, int out_size, void* d_ws, size_t ws_size,
                              hipStream_t stream) {
    const float* rois      = (const float*)d_in[0];
    const int*   gt_ids    = (const int*)d_in[1];
    const float* gt_boxes  = (const float*)d_in[2];
    const float* pos_score = (const float*)d_in[3];
    const float* neg_score = (const float*)d_in[4];
    float* out = (float*)d_out;

    // workspace layout (aligned); total 864 KB
    char* ws = (char*)d_ws;
    u32* pos_s = (u32*)(ws + 0);             // 16*6000*4 = 384000 B
    u32* neg_s = (u32*)(ws + 384000);        // 384000 B
    u8*  assign = (u8*)(ws + 768000);        // 96000 B

    dim3 gridA((NROI + 31) / 32, BIMG);      // 188 x 16
    iou_keys_kernel<<<gridA, 256, 0, stream>>>(rois, gt_ids, gt_boxes,
                                               pos_score, neg_score,
                                               pos_s, neg_s, assign);
    select_gather_kernel<<<BIMG, BSEL, 0, stream>>>(rois, gt_ids, gt_boxes,
                                                    pos_s, neg_s, assign, out);
}

// Round 4
// 93.380 us; speedup vs baseline: 2.2889x; 1.1334x over previous
//
#include <hip/hip_runtime.h>

// Problem constants (match reference)
#define BIMG 16
#define NROI 6000
#define NGT  256
#define TPOS 66
#define TNEG 134
#define TTOT 200
#define EPSF 1e-8f
#define INVALID_SCORE 0xFFFFFFFFu

typedef unsigned long long u64;
typedef unsigned int u32;
typedef unsigned char u8;

// ---------------- Kernel 1: IoU + score-keys + argmax ----------------
// Staging compacts gts into non-crowd / crowd LDS lists (skips invalid/padded).
// 8 threads per ROI, stride-8 over the compacted list (bank-conflict-free).
// grid (188, 16), block 256 -> 32 ROIs/block.
__global__ __launch_bounds__(256)
void iou_keys_kernel(const float* __restrict__ rois,
                     const int* __restrict__ gt_ids,
                     const float* __restrict__ gt_boxes,
                     const float* __restrict__ pos_score,
                     const float* __restrict__ neg_score,
                     u32* __restrict__ pos_s,
                     u32* __restrict__ neg_s,
                     u8* __restrict__ assign)
{
#pragma clang fp contract(off)
    const int b = blockIdx.y;
    __shared__ float4 s_ncbox[NGT];
    __shared__ float2 s_ncai[NGT];     // {area, g as float}
    __shared__ float4 s_crbox[NGT];
    __shared__ float  s_crarea[NGT];
    __shared__ int s_nccnt, s_crcnt;

    if (threadIdx.x == 0) { s_nccnt = 0; s_crcnt = 0; }
    __syncthreads();
    {
        const int g = threadIdx.x;     // 256 threads, 256 gts
        float4 gb = ((const float4*)gt_boxes)[b * NGT + g];
        bool valid = (gb.x != 0.f) || (gb.y != 0.f) || (gb.z != 0.f) || (gb.w != 0.f);
        int id = gt_ids[b * NGT + g];
        float area = (gb.z - gb.x) * (gb.w - gb.y);
        if (valid && id > 0) {
            int slot = atomicAdd(&s_nccnt, 1);
            s_ncbox[slot] = gb;
            s_ncai[slot] = make_float2(area, (float)g);
        } else if (valid && id < 0) {
            int slot = atomicAdd(&s_crcnt, 1);
            s_crbox[slot] = gb;
            s_crarea[slot] = area;
        }
    }
    __syncthreads();
    const int nccnt = s_nccnt;
    const int crcnt = s_crcnt;

    const int r_local = threadIdx.x >> 3;   // 0..31
    const int sub = threadIdx.x & 7;        // stride-8 partition of the lists
    const int n = blockIdx.x * 32 + r_local;
    const int n_eff = min(n, NROI - 1);

    float4 rb = ((const float4*)rois)[b * NROI + n_eff];
    const bool rvalid = (rb.x != 0.f) || (rb.y != 0.f) || (rb.z != 0.f) || (rb.w != 0.f);
    const float area_a = (rb.z - rb.x) * (rb.w - rb.y);

    float best = -1.0f;     // iou_nc_max (matches where(non_crowd, iou, -1) init)
    float bestg = 0.0f;     // argmax first-occurrence == min g among max ties
    float crmax = 0.0f;

    for (int i = sub; i < nccnt; i += 8) {
        float4 p0 = s_ncbox[i];
        float2 ai = s_ncai[i];
        float y1 = fmaxf(rb.x, p0.x);
        float x1 = fmaxf(rb.y, p0.y);
        float y2 = fminf(rb.z, p0.z);
        float x2 = fminf(rb.w, p0.w);
        float ih = fmaxf(y2 - y1, 0.0f);
        float iw = fmaxf(x2 - x1, 0.0f);
        float inter = ih * iw;
        float uni = fmaxf(area_a + ai.x - inter, EPSF);  // (a+b)-inter then max eps
        float iou = inter / uni;                          // precise f32 div (matches np)
        bool better = (iou > best) || ((iou == best) && (ai.y < bestg));
        if (better) { best = iou; bestg = ai.y; }
    }
    for (int i = sub; i < crcnt; i += 8) {
        float4 p0 = s_crbox[i];
        float y1 = fmaxf(rb.x, p0.x);
        float x1 = fmaxf(rb.y, p0.y);
        float y2 = fminf(rb.z, p0.z);
        float x2 = fminf(rb.w, p0.w);
        float ih = fmaxf(y2 - y1, 0.0f);
        float iw = fmaxf(x2 - x1, 0.0f);
        float inter = ih * iw;
        float uni = fmaxf(area_a + s_crarea[i] - inter, EPSF);
        crmax = fmaxf(crmax, inter / uni);
    }

    // butterfly merge across the 8 sub-lanes; tie -> smaller g (first occurrence)
    for (int m = 1; m <= 4; m <<= 1) {
        float ov = __shfl_xor(best, m);
        float og = __shfl_xor(bestg, m);
        float oc = __shfl_xor(crmax, m);
        if ((ov > best) || ((ov == best) && (og < bestg))) { best = ov; bestg = og; }
        crmax = fmaxf(crmax, oc);
    }

    if (sub == 0 && n < NROI) {
        u32 ps = INVALID_SCORE, ns = INVALID_SCORE;
        if (rvalid) {
            if (best >= 0.5f)
                ps = __float_as_uint(pos_score[b * NROI + n]);  // in [0,1): bits < 2^30
            if ((best < 0.5f) && (crmax < 0.001f))
                ns = __float_as_uint(neg_score[b * NROI + n]);
        }
        pos_s[b * NROI + n] = ps;
        neg_s[b * NROI + n] = ns;
        assign[b * NROI + n] = (u8)(int)bestg;
    }
}

// ---------------- Kernel 2: radix top-K select + fused gather epilogue ----------
// grid 32 = 16 images x {pos, neg}; the two sides are fully independent:
// neg side always ranks top-TNEG (truncation to neg_count happens at write time,
// identical to ranking top-Kneg since ranking is a consistent prefix), and
// recomputes pos_count from pos-key validity itself.
// 43-bit key = score_bits<<13 | (8191-n): order-isomorphic to stable
// argsort(-score). Radix over 11-bit digits with early exit to gather+rank
// once candidates fit in CAND_CAP.
#define BSEL 512
#define SLOTS 12            // 512*12 = 6144 >= 6000
#define CAND_CAP 256

struct SelShared {
    u32 hist[2048];
    u32 wtot[8];
    u32 wsuf[8];
    int pick;
    u32 higher;
    u32 pickpop;
    u32 count;
    u64 comp[CAND_CAP];
    int cnt;
    int sel[TNEG];
};

__device__ __forceinline__ int count_valid(const u32* __restrict__ src,
                                           int tid, int lane, SelShared* S)
{
    int myvalid = 0;
    for (int s = 0; s < SLOTS; ++s) {
        int idx = s * BSEL + tid;
        myvalid += (idx < NROI && src[idx] != INVALID_SCORE);
    }
    for (int off = 1; off < 64; off <<= 1) myvalid += __shfl_xor(myvalid, off);
    if (tid == 0) S->count = 0;
    __syncthreads();
    if (lane == 0) atomicAdd(&S->count, (u32)myvalid);
    __syncthreads();
    return (int)S->count;
}

// Ranks the top-min(K,total) keys into S->sel (roi indices). Returns total valid.
__device__ __forceinline__ int radix_select(const u32* __restrict__ src, int K,
                                            int tid, int lane, int w, SelShared* S)
{
    u32 sc[SLOTS];
    int myvalid = 0;
    for (int s = 0; s < SLOTS; ++s) {
        int idx = s * BSEL + tid;
        sc[s] = (idx < NROI) ? src[idx] : INVALID_SCORE;
        myvalid += (sc[s] != INVALID_SCORE);
    }
    for (int off = 1; off < 64; off <<= 1) myvalid += __shfl_xor(myvalid, off);
    if (tid == 0) S->count = 0;
    __syncthreads();
    if (lane == 0) atomicAdd(&S->count, (u32)myvalid);
    __syncthreads();
    const int total = (int)S->count;
    const int K0 = min(K, total);
    if (K0 <= 0) return total;          // uniform across block

    int Krem = K0;
    u64 prefix = 0ull, mask = 0ull;
    int cand = total;                   // (# definitely above) + (bucket population)

    for (int p = 3; p >= 0; --p) {
        if (cand <= CAND_CAP) break;    // uniform
        const int shift = p * 11;
        for (int i = tid; i < 2048; i += BSEL) S->hist[i] = 0;
        __syncthreads();
        for (int s = 0; s < SLOTS; ++s) {
            if (sc[s] != INVALID_SCORE) {
                u64 k = ((u64)sc[s] << 13) | (u64)(8191 - (s * BSEL + tid));
                if ((k & mask) == prefix)
                    atomicAdd(&S->hist[(u32)(k >> shift) & 2047u], 1u);
            }
        }
        __syncthreads();
        // block-wide suffix scan over 2048 buckets (4 per thread)
        u32 local = S->hist[4 * tid] + S->hist[4 * tid + 1]
                  + S->hist[4 * tid + 2] + S->hist[4 * tid + 3];
        u32 suf = local;
        for (int off = 1; off < 64; off <<= 1) {
            u32 v = __shfl_down(suf, off);
            if (lane + off < 64) suf += v;
        }
        if (lane == 0) S->wtot[w] = suf;
        __syncthreads();
        if (tid < 8) {
            u32 t = 0;
            for (int j = tid + 1; j < 8; ++j) t += S->wtot[j];
            S->wsuf[tid] = t;
        }
        __syncthreads();
        u32 Sincl = suf + S->wsuf[w];   // suffix including bucket 4*tid
        for (int k2 = 0; k2 < 4; ++k2) {
            u32 h = S->hist[4 * tid + k2];
            u32 Snext = Sincl - h;      // count with digit strictly greater
            if (Sincl >= (u32)Krem && Snext < (u32)Krem) {  // unique crossing
                S->pick = 4 * tid + k2;
                S->higher = Snext;
                S->pickpop = h;
            }
            Sincl = Snext;
        }
        __syncthreads();
        prefix |= ((u64)(u32)S->pick) << shift;
        mask   |= (2047ull << shift);
        Krem   -= (int)S->higher;
        cand    = (K0 - Krem) + (int)S->pickpop;
        __syncthreads();
    }

    // gather candidates: (k & mask) >= prefix  (count == cand <= CAND_CAP)
    if (tid == 0) S->cnt = 0;
    __syncthreads();
    for (int s = 0; s < SLOTS; ++s) {
        if (sc[s] != INVALID_SCORE) {
            u64 k = ((u64)sc[s] << 13) | (u64)(8191 - (s * BSEL + tid));
            if ((k & mask) >= prefix) {
                int pos = atomicAdd(&S->cnt, 1);
                S->comp[pos] = k;
            }
        }
    }
    __syncthreads();
    const int Cnt = S->cnt;
    if (tid < Cnt) {
        u64 k = S->comp[tid];
        int rank = 0;
        for (int j = 0; j < Cnt; ++j) rank += (S->comp[j] > k);
        if (rank < K0) S->sel[rank] = 8191 - (int)(k & 8191ull);
    }
    __syncthreads();
    return total;
}

__global__ __launch_bounds__(BSEL)
void select_gather_kernel(const float* __restrict__ rois,
                          const int* __restrict__ gt_ids,
                          const float* __restrict__ gt_boxes,
                          const u32* __restrict__ pos_s,
                          const u32* __restrict__ neg_s,
                          const u8* __restrict__ assign,
                          float* __restrict__ out)
{
#pragma clang fp contract(off)
    __shared__ SelShared S;
    const int b = blockIdx.x >> 1;
    const int side = blockIdx.x & 1;
    const int tid = threadIdx.x;
    const int lane = tid & 63;
    const int w = tid >> 6;

    float* out_rois = out;                                 // [16][200][4]
    float* out_ids  = out + BIMG * TTOT * 4;               // [16][200]
    float* out_off  = out + BIMG * TTOT * 4 + BIMG * TTOT; // [16][200][4]

    if (side == 0) {
        // ---------------- positives ----------------
        const int pos_total = radix_select(pos_s + (size_t)b * NROI, TPOS,
                                           tid, lane, w, &S);
        const int pos_count = min(pos_total, TPOS);

        if (tid < TPOS) {
            const int base = b * TTOT + tid;
            float4 ro  = make_float4(0.f, 0.f, 0.f, 0.f);
            float  idv = 0.f;
            float4 off = make_float4(0.f, 0.f, 0.f, 0.f);
            if (tid < pos_count) {
                int n = S.sel[tid];
                float4 rb = ((const float4*)rois)[b * NROI + n];
                ro = rb;
                int g = (int)assign[b * NROI + n];
                float4 gb = ((const float4*)gt_boxes)[b * NGT + g];
                idv = (float)gt_ids[b * NGT + g];

                float h  = fmaxf(rb.z - rb.x, EPSF);
                float wd = fmaxf(rb.w - rb.y, EPSF);
                float cy = rb.x + 0.5f * h;
                float cx = rb.y + 0.5f * wd;
                float gh = fmaxf(gb.z - gb.x, EPSF);
                float gw = fmaxf(gb.w - gb.y, EPSF);
                float gcy = gb.x + 0.5f * gh;
                float gcx = gb.y + 0.5f * gw;
                off.x = ((gcy - cy) / h)  / 0.1f;
                off.y = ((gcx - cx) / wd) / 0.1f;
                off.z = logf(gh / h)  / 0.2f;
                off.w = logf(gw / wd) / 0.2f;
            }
            ((float4*)out_rois)[base] = ro;
            out_ids[base] = idv;
            ((float4*)out_off)[base] = off;
        }
    } else {
        // ---------------- negatives ----------------
        // pos_count from pos-key validity (independent of pos block)
        const int pos_total = count_valid(pos_s + (size_t)b * NROI, tid, lane, &S);
        const int pos_count = min(pos_total, TPOS);
        const float ratio_inv = (float)(1.0 / 0.33);         // f32(1/RATIO)
        const int neg_target = (int)(ratio_inv * (float)pos_count) - pos_count;

        // rank top-TNEG always; truncate at write time (identical prefix)
        const int neg_total = radix_select(neg_s + (size_t)b * NROI, TNEG,
                                           tid, lane, w, &S);
        const int neg_count = max(0, min(neg_total, min(neg_target, TNEG)));

        if (tid < TNEG) {
            const int base = b * TTOT + TPOS + tid;
            float4 ro = make_float4(0.f, 0.f, 0.f, 0.f);
            if (tid < neg_count) {
                int n = S.sel[tid];
                ro = ((const float4*)rois)[b * NROI + n];
            }
            ((float4*)out_rois)[base] = ro;
            out_ids[base] = 0.f;
            ((float4*)out_off)[base] = make_float4(0.f, 0.f, 0.f, 0.f);
        }
    }
}

extern "C" void kernel_launch(void* const* d_in, const int* in_sizes, int n_in,
                              void* d_out, int out_size, void* d_ws, size_t ws_size,
                              hipStream_t stream) {
    const float* rois      = (const float*)d_in[0];
    const int*   gt_ids    = (const int*)d_in[1];
    const float* gt_boxes  = (const float*)d_in[2];
    const float* pos_score = (const float*)d_in[3];
    const float* neg_score = (const float*)d_in[4];
    float* out = (float*)d_out;

    // workspace layout; total 864 KB
    char* ws = (char*)d_ws;
    u32* pos_s = (u32*)(ws + 0);             // 16*6000*4 = 384000 B
    u32* neg_s = (u32*)(ws + 384000);        // 384000 B
    u8*  assign = (u8*)(ws + 768000);        // 96000 B

    dim3 gridA((NROI + 31) / 32, BIMG);      // 188 x 16
    iou_keys_kernel<<<gridA, 256, 0, stream>>>(rois, gt_ids, gt_boxes,
                                               pos_score, neg_score,
                                               pos_s, neg_s, assign);
    select_gather_kernel<<<BIMG * 2, BSEL, 0, stream>>>(rois, gt_ids, gt_boxes,
                                                        pos_s, neg_s, assign, out);
}